// Round 1
// baseline (1946.886 us; speedup 1.0000x reference)
//
#include <hip/hip_runtime.h>

#define N_NODES 10000
#define N_EDGES 30000
#define NODE_DIM 75
#define BOND_DIM 16
#define IN_DIM 64
#define INTERNAL 128
#define FP_DIM 4096
#define N_GRAPHS 16
#define DEPTH 3

// graph boundaries via binary search on sorted batch
__global__ void k_bounds(const int* __restrict__ batch, int* __restrict__ gstart) {
    int g = threadIdx.x;
    if (g > N_GRAPHS) return;
    int lo = 0, hi = N_NODES;
    while (lo < hi) { int mid = (lo + hi) >> 1; if (batch[mid] < g) lo = mid + 1; else hi = mid; }
    gstart[g] = lo;
}

// msg0 = relu(x @ W_ae + b_ae)   [10000,75]x[75,64]
__global__ void k_atom_expand(const float* __restrict__ x, const float* __restrict__ W,
                              const float* __restrict__ b, float* __restrict__ msg) {
    int n = blockIdx.x;
    int o = threadIdx.x;          // 64
    __shared__ float xr[NODE_DIM];
    if (o < NODE_DIM) xr[o] = x[(size_t)n * NODE_DIM + o];
    if (o + 64 < NODE_DIM) xr[o + 64] = x[(size_t)n * NODE_DIM + o + 64];
    __syncthreads();
    float acc = b[o];
    #pragma unroll
    for (int k = 0; k < NODE_DIM; ++k) acc = fmaf(xr[k], W[k * IN_DIM + o], acc);
    msg[(size_t)n * IN_DIM + o] = fmaxf(acc, 0.f);
}

// h = relu(edge_attr @ W_e1 + b_e1)   [30000,16]x[16,128]  (depth-invariant)
__global__ void k_edge_h(const float* __restrict__ ea, const float* __restrict__ W1,
                         const float* __restrict__ b1, float* __restrict__ h) {
    int e = blockIdx.x;
    int j = threadIdx.x;          // 128
    __shared__ float r[BOND_DIM];
    if (j < BOND_DIM) r[j] = ea[(size_t)e * BOND_DIM + j];
    __syncthreads();
    float acc = b1[j];
    #pragma unroll
    for (int k = 0; k < BOND_DIM; ++k) acc = fmaf(r[k], W1[k * INTERNAL + j], acc);
    h[(size_t)e * INTERNAL + j] = fmaxf(acc, 0.f);
}

// per-dst edge counts for the two masks (depth-invariant)
__global__ void k_counts(const float* __restrict__ ea, const int* __restrict__ dst,
                         float* __restrict__ cntC, float* __restrict__ cntS) {
    int e = blockIdx.x * blockDim.x + threadIdx.x;
    if (e >= N_EDGES) return;
    if (ea[(size_t)e * BOND_DIM + (BOND_DIM - 1)] == 0.f) atomicAdd(&cntC[dst[e]], 1.f);
    else atomicAdd(&cntS[dst[e]], 1.f);
}

// per_edge[e,o] = sum_k h[e,k] * sum_i m[src[e],i] * W2[k, i*64+o]  + sum_i m[e,i]*b2[i*64+o]
// = GEMM C[E,64] = A[E,8192] @ W2'[8192,64], A formed on the fly. Scatter fused in epilogue.
__global__ __launch_bounds__(256) void k_per_edge_scatter(
    const float* __restrict__ h, const float* __restrict__ msg,
    const int* __restrict__ src, const int* __restrict__ dst,
    const float* __restrict__ ea,
    const float* __restrict__ W2, const float* __restrict__ b2,
    float* __restrict__ aggC, float* __restrict__ aggS)
{
    __shared__ float m_lds[64][68];          // +4 pad: 2-way-max bank aliasing on row reads
    __shared__ float h_lds[64 * INTERNAL];   // 32 KB
    __shared__ float w_lds[4096];            // one W2 row (k fixed), 16 KB
    const int tid = threadIdx.x;
    const int e0 = blockIdx.x * 64;
    const int tx = tid & 15;                 // output cols tx*4 .. tx*4+3
    const int ty = tid >> 4;                 // edges ty + 16*j

    for (int v = tid; v < 2048; v += 256) {  // stage h tile [64][128]
        int idx = v * 4;
        int row = idx >> 7, col = idx & 127;
        int e = e0 + row; if (e >= N_EDGES) e = N_EDGES - 1;
        *(float4*)&h_lds[idx] = *(const float4*)&h[(size_t)e * INTERNAL + col];
    }
    for (int v = tid; v < 1024; v += 256) {  // gather m tile [64][64]
        int idx = v * 4;
        int row = idx >> 6, col = idx & 63;
        int e = e0 + row; if (e >= N_EDGES) e = N_EDGES - 1;
        *(float4*)&m_lds[row][col] = *(const float4*)&msg[(size_t)src[e] * IN_DIM + col];
    }

    float acc[4][4];
    #pragma unroll
    for (int j = 0; j < 4; ++j)
        #pragma unroll
        for (int l = 0; l < 4; ++l) acc[j][l] = 0.f;

    // k = 0..127: W2 rows; k = 128: bias row (h := 1)
    for (int k = 0; k <= INTERNAL; ++k) {
        __syncthreads();
        if (k < INTERNAL) {
            const float* wr = W2 + (size_t)k * 4096;
            for (int v = tid; v < 1024; v += 256)
                *(float4*)&w_lds[v * 4] = *(const float4*)&wr[v * 4];
        } else {
            for (int v = tid; v < 1024; v += 256)
                *(float4*)&w_lds[v * 4] = *(const float4*)&b2[v * 4];
        }
        __syncthreads();
        float he[4];
        #pragma unroll
        for (int j = 0; j < 4; ++j)
            he[j] = (k < INTERNAL) ? h_lds[(ty + 16 * j) * INTERNAL + k] : 1.f;
        #pragma unroll 2
        for (int i = 0; i < 64; i += 2) {
            float4 wa = *(const float4*)&w_lds[i * 64 + tx * 4];
            float4 wb = *(const float4*)&w_lds[(i + 1) * 64 + tx * 4];
            #pragma unroll
            for (int j = 0; j < 4; ++j) {
                float2 mv = *(const float2*)&m_lds[ty + 16 * j][i];
                float pa = he[j] * mv.x;
                float pb = he[j] * mv.y;
                acc[j][0] = fmaf(pa, wa.x, fmaf(pb, wb.x, acc[j][0]));
                acc[j][1] = fmaf(pa, wa.y, fmaf(pb, wb.y, acc[j][1]));
                acc[j][2] = fmaf(pa, wa.z, fmaf(pb, wb.z, acc[j][2]));
                acc[j][3] = fmaf(pa, wa.w, fmaf(pb, wb.w, acc[j][3]));
            }
        }
    }

    // fused masked scatter-add to dst
    #pragma unroll
    for (int j = 0; j < 4; ++j) {
        int e = e0 + ty + 16 * j;
        if (e < N_EDGES) {
            float* agg = (ea[(size_t)e * BOND_DIM + (BOND_DIM - 1)] == 0.f) ? aggC : aggS;
            float* p = &agg[(size_t)dst[e] * IN_DIM + tx * 4];
            atomicAdd(p + 0, acc[j][0]);
            atomicAdd(p + 1, acc[j][1]);
            atomicAdd(p + 2, acc[j][2]);
            atomicAdd(p + 3, acc[j][3]);
        }
    }
}

// msg_new = relu(mean_cov + mean_spa + 2*(msg_old @ W_root + b_conv))
__global__ void k_combine(const float* __restrict__ msg_old, const float* __restrict__ Wr,
                          const float* __restrict__ bc,
                          const float* __restrict__ aggC, const float* __restrict__ aggS,
                          const float* __restrict__ cntC, const float* __restrict__ cntS,
                          float* __restrict__ msg_new) {
    int n = blockIdx.x, o = threadIdx.x;   // 64
    __shared__ float r[IN_DIM];
    r[o] = msg_old[(size_t)n * IN_DIM + o];
    __syncthreads();
    float root = bc[o];
    #pragma unroll
    for (int k = 0; k < IN_DIM; ++k) root = fmaf(r[k], Wr[k * IN_DIM + o], root);
    float cc = cntC[n], cs = cntS[n];
    float mc = (cc > 0.f) ? aggC[(size_t)n * IN_DIM + o] / cc : 0.f;
    float ms = (cs > 0.f) ? aggS[(size_t)n * IN_DIM + o] / cs : 0.f;
    msg_new[(size_t)n * IN_DIM + o] = fmaxf(mc + ms + 2.f * root, 0.f);
}

// out[g,:] += sum_{n in graph g} relu(msg[n] @ W_fp + b_fp)   (fused GEMM + add-pool)
__global__ __launch_bounds__(256) void k_fp_pool(
    const float* __restrict__ msg, const float* __restrict__ Wfp,
    const float* __restrict__ bfp, const int* __restrict__ gstart,
    float* __restrict__ out) {
    int c = blockIdx.x * 256 + threadIdx.x;   // fp column
    int g = blockIdx.y;                       // graph
    float w[IN_DIM];
    #pragma unroll
    for (int k = 0; k < IN_DIM; ++k) w[k] = Wfp[(size_t)k * FP_DIM + c];
    float bias = bfp[c];
    int n0 = gstart[g], n1 = gstart[g + 1];
    int len = n1 - n0;
    int chunk = (len + (int)gridDim.z - 1) / (int)gridDim.z;
    int s = n0 + (int)blockIdx.z * chunk;
    int e = min(s + chunk, n1);
    float acc = 0.f;
    __shared__ float mr[8][IN_DIM];
    for (int nb = s; nb < e; nb += 8) {
        __syncthreads();
        int cnt = min(8, e - nb);
        for (int v = (int)threadIdx.x; v < cnt * IN_DIM; v += 256)
            ((float*)mr)[v] = msg[(size_t)nb * IN_DIM + v];
        __syncthreads();
        for (int rr = 0; rr < cnt; ++rr) {
            float sv = bias;
            #pragma unroll
            for (int k = 0; k < IN_DIM; k += 4) {
                float4 mv = *(const float4*)&mr[rr][k];
                sv = fmaf(mv.x, w[k], sv);
                sv = fmaf(mv.y, w[k + 1], sv);
                sv = fmaf(mv.z, w[k + 2], sv);
                sv = fmaf(mv.w, w[k + 3], sv);
            }
            acc += fmaxf(sv, 0.f);
        }
    }
    atomicAdd(&out[(size_t)g * FP_DIM + c], acc);
}

extern "C" void kernel_launch(void* const* d_in, const int* in_sizes, int n_in,
                              void* d_out, int out_size, void* d_ws, size_t ws_size,
                              hipStream_t stream) {
    const float* x        = (const float*)d_in[0];
    const int*   eidx     = (const int*)d_in[1];
    const float* ea       = (const float*)d_in[2];
    const int*   batch    = (const int*)d_in[3];
    const float* W_ae     = (const float*)d_in[4];
    const float* b_ae     = (const float*)d_in[5];
    const float* W_e1     = (const float*)d_in[6];
    const float* b_e1     = (const float*)d_in[7];
    const float* W_e2     = (const float*)d_in[8];
    const float* b_e2     = (const float*)d_in[9];
    const float* W_root   = (const float*)d_in[10];
    const float* b_conv   = (const float*)d_in[11];
    const float* W_fp     = (const float*)d_in[12];
    const float* b_fp     = (const float*)d_in[13];
    const int* src = eidx;
    const int* dst = eidx + N_EDGES;
    float* out = (float*)d_out;

    float* ws   = (float*)d_ws;
    float* msgA = ws;                                   // 640000
    float* msgB = msgA + (size_t)N_NODES * IN_DIM;      // 640000
    float* h    = msgB + (size_t)N_NODES * IN_DIM;      // 3840000
    float* aggC = h + (size_t)N_EDGES * INTERNAL;       // 640000
    float* aggS = aggC + (size_t)N_NODES * IN_DIM;      // 640000
    float* cntC = aggS + (size_t)N_NODES * IN_DIM;      // 10000
    float* cntS = cntC + N_NODES;                       // 10000
    int*   gst  = (int*)(cntS + N_NODES);               // 17 (+pad)

    size_t needed = ((size_t)(2 * N_NODES * IN_DIM) + (size_t)N_EDGES * INTERNAL
                     + (size_t)2 * N_NODES * IN_DIM + 2 * N_NODES + 32) * 4;
    hipMemsetAsync(out, 0, (size_t)out_size * sizeof(float), stream);
    if (ws_size < needed) return;  // fail loudly (out=0) rather than corrupt

    hipMemsetAsync(cntC, 0, 2 * (size_t)N_NODES * sizeof(float), stream);
    k_bounds<<<1, 32, 0, stream>>>(batch, gst);
    k_atom_expand<<<N_NODES, 64, 0, stream>>>(x, W_ae, b_ae, msgA);
    k_edge_h<<<N_EDGES, 128, 0, stream>>>(ea, W_e1, b_e1, h);
    k_counts<<<(N_EDGES + 255) / 256, 256, 0, stream>>>(ea, dst, cntC, cntS);

    float* cur = msgA;
    float* nxt = msgB;
    for (int d = 0; d < DEPTH; ++d) {
        hipMemsetAsync(aggC, 0, 2 * (size_t)N_NODES * IN_DIM * sizeof(float), stream);
        k_per_edge_scatter<<<(N_EDGES + 63) / 64, 256, 0, stream>>>(
            h, cur, src, dst, ea, W_e2, b_e2, aggC, aggS);
        k_combine<<<N_NODES, 64, 0, stream>>>(cur, W_root, b_conv, aggC, aggS, cntC, cntS, nxt);
        k_fp_pool<<<dim3(FP_DIM / 256, N_GRAPHS, 4), 256, 0, stream>>>(nxt, W_fp, b_fp, gst, out);
        float* t = cur; cur = nxt; nxt = t;
    }
}

// Round 2
// 845.329 us; speedup vs baseline: 2.3031x; 2.3031x over previous
//
#include <hip/hip_runtime.h>
#include <hip/hip_fp16.h>

#define N_NODES 10000
#define N_EDGES 30000
#define NODE_DIM 75
#define BOND_DIM 16
#define IN_DIM 64
#define INTERNAL 128
#define FP_DIM 4096
#define N_GRAPHS 16
#define DEPTH 3

typedef _Float16 half8v __attribute__((ext_vector_type(8)));
typedef float float4v __attribute__((ext_vector_type(4)));

// graph boundaries via binary search on sorted batch
__global__ void k_bounds(const int* __restrict__ batch, int* __restrict__ gstart) {
    int g = threadIdx.x;
    if (g > N_GRAPHS) return;
    int lo = 0, hi = N_NODES;
    while (lo < hi) { int mid = (lo + hi) >> 1; if (batch[mid] < g) lo = mid + 1; else hi = mid; }
    gstart[g] = lo;
}

// msg0 = relu(x @ W_ae + b_ae)   [10000,75]x[75,64]
__global__ void k_atom_expand(const float* __restrict__ x, const float* __restrict__ W,
                              const float* __restrict__ b, float* __restrict__ msg) {
    int n = blockIdx.x;
    int o = threadIdx.x;          // 64
    __shared__ float xr[NODE_DIM];
    if (o < NODE_DIM) xr[o] = x[(size_t)n * NODE_DIM + o];
    if (o + 64 < NODE_DIM) xr[o + 64] = x[(size_t)n * NODE_DIM + o + 64];
    __syncthreads();
    float acc = b[o];
    #pragma unroll
    for (int k = 0; k < NODE_DIM; ++k) acc = fmaf(xr[k], W[k * IN_DIM + o], acc);
    msg[(size_t)n * IN_DIM + o] = fmaxf(acc, 0.f);
}

// h = relu(edge_attr @ W_e1 + b_e1)  -> fp16   [30000,16]x[16,128]  (depth-invariant)
__global__ void k_edge_h16(const float* __restrict__ ea, const float* __restrict__ W1,
                           const float* __restrict__ b1, __half* __restrict__ h) {
    int e = blockIdx.x;
    int j = threadIdx.x;          // 128
    __shared__ float r[BOND_DIM];
    if (j < BOND_DIM) r[j] = ea[(size_t)e * BOND_DIM + j];
    __syncthreads();
    float acc = b1[j];
    #pragma unroll
    for (int k = 0; k < BOND_DIM; ++k) acc = fmaf(r[k], W1[k * INTERNAL + j], acc);
    h[(size_t)e * INTERNAL + j] = __float2half(fmaxf(acc, 0.f));
}

// fp32 h variant for small-workspace fallback
__global__ void k_edge_h(const float* __restrict__ ea, const float* __restrict__ W1,
                         const float* __restrict__ b1, float* __restrict__ h) {
    int e = blockIdx.x;
    int j = threadIdx.x;          // 128
    __shared__ float r[BOND_DIM];
    if (j < BOND_DIM) r[j] = ea[(size_t)e * BOND_DIM + j];
    __syncthreads();
    float acc = b1[j];
    #pragma unroll
    for (int k = 0; k < BOND_DIM; ++k) acc = fmaf(r[k], W1[k * INTERNAL + j], acc);
    h[(size_t)e * INTERNAL + j] = fmaxf(acc, 0.f);
}

// transpose-convert W2 [128][4096] fp32 -> W2T [4096][128] fp16 (one-time, 1MB)
__global__ void k_w2t(const float* __restrict__ W2, __half* __restrict__ W2T) {
    int idx = blockIdx.x * 256 + threadIdx.x;     // 524288 total
    int k = idx >> 12;
    int n = idx & 4095;
    W2T[(size_t)n * INTERNAL + k] = __float2half(W2[idx]);
}

// per-dst edge counts for the two masks (depth-invariant)
__global__ void k_counts(const float* __restrict__ ea, const int* __restrict__ dst,
                         float* __restrict__ cntC, float* __restrict__ cntS) {
    int e = blockIdx.x * blockDim.x + threadIdx.x;
    if (e >= N_EDGES) return;
    if (ea[(size_t)e * BOND_DIM + (BOND_DIM - 1)] == 0.f) atomicAdd(&cntC[dst[e]], 1.f);
    else atomicAdd(&cntS[dst[e]], 1.f);
}

// One-time MFMA GEMM: w[E,4096] = h16[E,128] @ W2 + b2, stored fp16.
// A frag: row = lane&15, k = (lane>>4)*8+j (contiguous in h row).
// B frag: col = lane&15, k = (lane>>4)*8+j (contiguous in W2T row).
// C/D: col = lane&15, row = (lane>>4)*4+reg.
__global__ __launch_bounds__(256) void k_wgemm(
    const __half* __restrict__ h16, const __half* __restrict__ W2T,
    const float* __restrict__ b2, __half* __restrict__ w)
{
    const int tid = threadIdx.x;
    const int lane = tid & 63;
    const int wv = tid >> 6;                 // wave 0..3: edge sub-tiles
    const int e_blk = blockIdx.x * 128;
    const int n_blk = blockIdx.y * 128;
    const int rowA = lane & 15;
    const int kHi  = (lane >> 4) * 8;

    half8v a[2][4];
    #pragma unroll
    for (int mi = 0; mi < 2; ++mi) {
        int e = e_blk + wv * 32 + mi * 16 + rowA;
        if (e >= N_EDGES) e = N_EDGES - 1;
        const half8v* arow = (const half8v*)(h16 + (size_t)e * INTERNAL);
        #pragma unroll
        for (int kk = 0; kk < 4; ++kk)
            a[mi][kk] = arow[kk * 4 + (kHi >> 3)];
    }

    float4v acc[2][8];
    #pragma unroll
    for (int mi = 0; mi < 2; ++mi)
        #pragma unroll
        for (int ni = 0; ni < 8; ++ni)
            acc[mi][ni] = (float4v){0.f, 0.f, 0.f, 0.f};

    #pragma unroll
    for (int ni = 0; ni < 8; ++ni) {
        int n = n_blk + ni * 16 + rowA;
        const half8v* brow = (const half8v*)(W2T + (size_t)n * INTERNAL);
        #pragma unroll
        for (int kk = 0; kk < 4; ++kk) {
            half8v bf = brow[kk * 4 + (kHi >> 3)];
            acc[0][ni] = __builtin_amdgcn_mfma_f32_16x16x32_f16(a[0][kk], bf, acc[0][ni], 0, 0, 0);
            acc[1][ni] = __builtin_amdgcn_mfma_f32_16x16x32_f16(a[1][kk], bf, acc[1][ni], 0, 0, 0);
        }
    }

    const int colD = lane & 15;
    const int rowD0 = (lane >> 4) * 4;
    #pragma unroll
    for (int mi = 0; mi < 2; ++mi) {
        int ebase = e_blk + wv * 32 + mi * 16 + rowD0;
        #pragma unroll
        for (int ni = 0; ni < 8; ++ni) {
            int n = n_blk + ni * 16 + colD;
            float bias = b2[n];
            #pragma unroll
            for (int r = 0; r < 4; ++r) {
                int e = ebase + r;
                if (e < N_EDGES)
                    w[(size_t)e * FP_DIM + n] = __float2half(acc[mi][ni][r] + bias);
            }
        }
    }
}

// Per depth: per_edge[e] = m[src[e]] @ w[e] (64x64 fp16), fused masked scatter-add.
// One wave per edge; streams the 8KB w[e] fully coalesced.
__global__ __launch_bounds__(256) void k_edge_apply(
    const float* __restrict__ msg, const __half* __restrict__ w,
    const int* __restrict__ src, const int* __restrict__ dst,
    const float* __restrict__ ea,
    float* __restrict__ aggC, float* __restrict__ aggS)
{
    const int lane = threadIdx.x & 63;
    const int e = blockIdx.x * 4 + (threadIdx.x >> 6);
    if (e >= N_EDGES) return;
    const float mv = msg[(size_t)src[e] * IN_DIM + lane];
    const half8v* wrow = (const half8v*)(w + (size_t)e * FP_DIM);
    const int ig = lane >> 3;        // i-subgroup
    const int oc = lane & 7;         // o-chunk (8 outputs)
    float acc[8] = {0.f, 0.f, 0.f, 0.f, 0.f, 0.f, 0.f, 0.f};
    #pragma unroll
    for (int t = 0; t < 8; ++t) {
        int i = ig + 8 * t;
        half8v w8 = wrow[i * 8 + oc];
        float mi = __shfl(mv, i);
        #pragma unroll
        for (int j = 0; j < 8; ++j) acc[j] = fmaf(mi, (float)w8[j], acc[j]);
    }
    #pragma unroll
    for (int d = 8; d < 64; d <<= 1)
        #pragma unroll
        for (int j = 0; j < 8; ++j) acc[j] += __shfl_xor(acc[j], d);
    if (ig == 0) {
        float* agg = (ea[(size_t)e * BOND_DIM + (BOND_DIM - 1)] == 0.f) ? aggC : aggS;
        float* p = &agg[(size_t)dst[e] * IN_DIM + oc * 8];
        #pragma unroll
        for (int j = 0; j < 8; ++j) atomicAdd(p + j, acc[j]);
    }
}

// ===== fallback (small workspace): round-1 fused per-edge GEMM =====
__global__ __launch_bounds__(256) void k_per_edge_scatter(
    const float* __restrict__ h, const float* __restrict__ msg,
    const int* __restrict__ src, const int* __restrict__ dst,
    const float* __restrict__ ea,
    const float* __restrict__ W2, const float* __restrict__ b2,
    float* __restrict__ aggC, float* __restrict__ aggS)
{
    __shared__ float m_lds[64][68];
    __shared__ float h_lds[64 * INTERNAL];
    __shared__ float w_lds[4096];
    const int tid = threadIdx.x;
    const int e0 = blockIdx.x * 64;
    const int tx = tid & 15;
    const int ty = tid >> 4;

    for (int v = tid; v < 2048; v += 256) {
        int idx = v * 4;
        int row = idx >> 7, col = idx & 127;
        int e = e0 + row; if (e >= N_EDGES) e = N_EDGES - 1;
        *(float4*)&h_lds[idx] = *(const float4*)&h[(size_t)e * INTERNAL + col];
    }
    for (int v = tid; v < 1024; v += 256) {
        int idx = v * 4;
        int row = idx >> 6, col = idx & 63;
        int e = e0 + row; if (e >= N_EDGES) e = N_EDGES - 1;
        *(float4*)&m_lds[row][col] = *(const float4*)&msg[(size_t)src[e] * IN_DIM + col];
    }

    float acc[4][4];
    #pragma unroll
    for (int j = 0; j < 4; ++j)
        #pragma unroll
        for (int l = 0; l < 4; ++l) acc[j][l] = 0.f;

    for (int k = 0; k <= INTERNAL; ++k) {
        __syncthreads();
        if (k < INTERNAL) {
            const float* wr = W2 + (size_t)k * 4096;
            for (int v = tid; v < 1024; v += 256)
                *(float4*)&w_lds[v * 4] = *(const float4*)&wr[v * 4];
        } else {
            for (int v = tid; v < 1024; v += 256)
                *(float4*)&w_lds[v * 4] = *(const float4*)&b2[v * 4];
        }
        __syncthreads();
        float he[4];
        #pragma unroll
        for (int j = 0; j < 4; ++j)
            he[j] = (k < INTERNAL) ? h_lds[(ty + 16 * j) * INTERNAL + k] : 1.f;
        #pragma unroll 2
        for (int i = 0; i < 64; i += 2) {
            float4 wa = *(const float4*)&w_lds[i * 64 + tx * 4];
            float4 wb = *(const float4*)&w_lds[(i + 1) * 64 + tx * 4];
            #pragma unroll
            for (int j = 0; j < 4; ++j) {
                float2 mvv = *(const float2*)&m_lds[ty + 16 * j][i];
                float pa = he[j] * mvv.x;
                float pb = he[j] * mvv.y;
                acc[j][0] = fmaf(pa, wa.x, fmaf(pb, wb.x, acc[j][0]));
                acc[j][1] = fmaf(pa, wa.y, fmaf(pb, wb.y, acc[j][1]));
                acc[j][2] = fmaf(pa, wa.z, fmaf(pb, wb.z, acc[j][2]));
                acc[j][3] = fmaf(pa, wa.w, fmaf(pb, wb.w, acc[j][3]));
            }
        }
    }

    #pragma unroll
    for (int j = 0; j < 4; ++j) {
        int e = e0 + ty + 16 * j;
        if (e < N_EDGES) {
            float* agg = (ea[(size_t)e * BOND_DIM + (BOND_DIM - 1)] == 0.f) ? aggC : aggS;
            float* p = &agg[(size_t)dst[e] * IN_DIM + tx * 4];
            atomicAdd(p + 0, acc[j][0]);
            atomicAdd(p + 1, acc[j][1]);
            atomicAdd(p + 2, acc[j][2]);
            atomicAdd(p + 3, acc[j][3]);
        }
    }
}

// msg_new = relu(mean_cov + mean_spa + 2*(msg_old @ W_root + b_conv))
__global__ void k_combine(const float* __restrict__ msg_old, const float* __restrict__ Wr,
                          const float* __restrict__ bc,
                          const float* __restrict__ aggC, const float* __restrict__ aggS,
                          const float* __restrict__ cntC, const float* __restrict__ cntS,
                          float* __restrict__ msg_new) {
    int n = blockIdx.x, o = threadIdx.x;   // 64
    __shared__ float r[IN_DIM];
    r[o] = msg_old[(size_t)n * IN_DIM + o];
    __syncthreads();
    float root = bc[o];
    #pragma unroll
    for (int k = 0; k < IN_DIM; ++k) root = fmaf(r[k], Wr[k * IN_DIM + o], root);
    float cc = cntC[n], cs = cntS[n];
    float mc = (cc > 0.f) ? aggC[(size_t)n * IN_DIM + o] / cc : 0.f;
    float ms = (cs > 0.f) ? aggS[(size_t)n * IN_DIM + o] / cs : 0.f;
    msg_new[(size_t)n * IN_DIM + o] = fmaxf(mc + ms + 2.f * root, 0.f);
}

// out[g,:] += sum_{n in graph g} relu(msg[n] @ W_fp + b_fp)
__global__ __launch_bounds__(256) void k_fp_pool(
    const float* __restrict__ msg, const float* __restrict__ Wfp,
    const float* __restrict__ bfp, const int* __restrict__ gstart,
    float* __restrict__ out) {
    int c = blockIdx.x * 256 + threadIdx.x;
    int g = blockIdx.y;
    float w[IN_DIM];
    #pragma unroll
    for (int k = 0; k < IN_DIM; ++k) w[k] = Wfp[(size_t)k * FP_DIM + c];
    float bias = bfp[c];
    int n0 = gstart[g], n1 = gstart[g + 1];
    int len = n1 - n0;
    int chunk = (len + (int)gridDim.z - 1) / (int)gridDim.z;
    int s = n0 + (int)blockIdx.z * chunk;
    int e = min(s + chunk, n1);
    float acc = 0.f;
    __shared__ float mr[8][IN_DIM];
    for (int nb = s; nb < e; nb += 8) {
        __syncthreads();
        int cnt = min(8, e - nb);
        for (int v = (int)threadIdx.x; v < cnt * IN_DIM; v += 256)
            ((float*)mr)[v] = msg[(size_t)nb * IN_DIM + v];
        __syncthreads();
        for (int rr = 0; rr < cnt; ++rr) {
            float sv = bias;
            #pragma unroll
            for (int k = 0; k < IN_DIM; k += 4) {
                float4 mv = *(const float4*)&mr[rr][k];
                sv = fmaf(mv.x, w[k], sv);
                sv = fmaf(mv.y, w[k + 1], sv);
                sv = fmaf(mv.z, w[k + 2], sv);
                sv = fmaf(mv.w, w[k + 3], sv);
            }
            acc += fmaxf(sv, 0.f);
        }
    }
    atomicAdd(&out[(size_t)g * FP_DIM + c], acc);
}

extern "C" void kernel_launch(void* const* d_in, const int* in_sizes, int n_in,
                              void* d_out, int out_size, void* d_ws, size_t ws_size,
                              hipStream_t stream) {
    const float* x        = (const float*)d_in[0];
    const int*   eidx     = (const int*)d_in[1];
    const float* ea       = (const float*)d_in[2];
    const int*   batch    = (const int*)d_in[3];
    const float* W_ae     = (const float*)d_in[4];
    const float* b_ae     = (const float*)d_in[5];
    const float* W_e1     = (const float*)d_in[6];
    const float* b_e1     = (const float*)d_in[7];
    const float* W_e2     = (const float*)d_in[8];
    const float* b_e2     = (const float*)d_in[9];
    const float* W_root   = (const float*)d_in[10];
    const float* b_conv   = (const float*)d_in[11];
    const float* W_fp     = (const float*)d_in[12];
    const float* b_fp     = (const float*)d_in[13];
    const int* src = eidx;
    const int* dst = eidx + N_EDGES;
    float* out = (float*)d_out;

    hipMemsetAsync(out, 0, (size_t)out_size * sizeof(float), stream);

    float* ws   = (float*)d_ws;
    // common region
    float* msgA = ws;                                   // 640000
    float* msgB = msgA + 640000;
    float* aggC = msgB + 640000;
    float* aggS = aggC + 640000;
    float* cntC = aggS + 640000;                        // 10000
    float* cntS = cntC + 10000;                         // 10000
    int*   gst  = (int*)(cntS + 10000);                 // 32

    // big path extras (fp16)
    __half* h16  = (__half*)(gst + 32);
    __half* W2T  = h16 + (size_t)N_EDGES * INTERNAL;    // 3,840,000 halfs
    __half* wbig = W2T + (size_t)FP_DIM * INTERNAL;     // 524,288 halfs

    size_t base_f32 = 4 * 640000 + 2 * 10000 + 32;
    size_t need_big = base_f32 * 4
                    + ((size_t)N_EDGES * INTERNAL + (size_t)FP_DIM * INTERNAL
                       + (size_t)N_EDGES * FP_DIM) * 2;
    size_t need_small = (base_f32 + (size_t)N_EDGES * INTERNAL) * 4;
    if (ws_size < need_small) return;   // fail loudly (out stays 0)

    hipMemsetAsync(cntC, 0, 2 * (size_t)N_NODES * sizeof(float), stream);
    k_bounds<<<1, 32, 0, stream>>>(batch, gst);
    k_atom_expand<<<N_NODES, 64, 0, stream>>>(x, W_ae, b_ae, msgA);
    k_counts<<<(N_EDGES + 255) / 256, 256, 0, stream>>>(ea, dst, cntC, cntS);

    bool big = (ws_size >= need_big);
    float* hf32 = (float*)(gst + 32);   // fallback layout reuses same region

    if (big) {
        k_edge_h16<<<N_EDGES, 128, 0, stream>>>(ea, W_e1, b_e1, h16);
        k_w2t<<<(FP_DIM * INTERNAL) / 256, 256, 0, stream>>>(W_e2, W2T);
        k_wgemm<<<dim3((N_EDGES + 127) / 128, FP_DIM / 128), 256, 0, stream>>>(
            h16, W2T, b_e2, wbig);
    } else {
        k_edge_h<<<N_EDGES, 128, 0, stream>>>(ea, W_e1, b_e1, hf32);
    }

    float* cur = msgA;
    float* nxt = msgB;
    for (int d = 0; d < DEPTH; ++d) {
        hipMemsetAsync(aggC, 0, 2 * (size_t)N_NODES * IN_DIM * sizeof(float), stream);
        if (big) {
            k_edge_apply<<<(N_EDGES + 3) / 4, 256, 0, stream>>>(
                cur, wbig, src, dst, ea, aggC, aggS);
        } else {
            k_per_edge_scatter<<<(N_EDGES + 63) / 64, 256, 0, stream>>>(
                hf32, cur, src, dst, ea, W_e2, b_e2, aggC, aggS);
        }
        k_combine<<<N_NODES, 64, 0, stream>>>(cur, W_root, b_conv, aggC, aggS, cntC, cntS, nxt);
        k_fp_pool<<<dim3(FP_DIM / 256, N_GRAPHS, 4), 256, 0, stream>>>(nxt, W_fp, b_fp, gst, out);
        float* t = cur; cur = nxt; nxt = t;
    }
}

// Round 3
// 598.550 us; speedup vs baseline: 3.2527x; 1.4123x over previous
//
#include <hip/hip_runtime.h>
#include <hip/hip_fp16.h>

#define N_NODES 10000
#define N_EDGES 30000
#define NODE_DIM 75
#define BOND_DIM 16
#define IN_DIM 64
#define INTERNAL 128
#define FP_DIM 4096
#define N_GRAPHS 16
#define DEPTH 3

typedef _Float16 half8v __attribute__((ext_vector_type(8)));
typedef _Float16 half4v __attribute__((ext_vector_type(4)));
typedef float float4v __attribute__((ext_vector_type(4)));

// graph boundaries via binary search on sorted batch
__global__ void k_bounds(const int* __restrict__ batch, int* __restrict__ gstart) {
    int g = threadIdx.x;
    if (g > N_GRAPHS) return;
    int lo = 0, hi = N_NODES;
    while (lo < hi) { int mid = (lo + hi) >> 1; if (batch[mid] < g) lo = mid + 1; else hi = mid; }
    gstart[g] = lo;
}

// msg0 = relu(x @ W_ae + b_ae)   [10000,75]x[75,64]
__global__ void k_atom_expand(const float* __restrict__ x, const float* __restrict__ W,
                              const float* __restrict__ b, float* __restrict__ msg) {
    int n = blockIdx.x;
    int o = threadIdx.x;          // 64
    __shared__ float xr[NODE_DIM];
    if (o < NODE_DIM) xr[o] = x[(size_t)n * NODE_DIM + o];
    if (o + 64 < NODE_DIM) xr[o + 64] = x[(size_t)n * NODE_DIM + o + 64];
    __syncthreads();
    float acc = b[o];
    #pragma unroll
    for (int k = 0; k < NODE_DIM; ++k) acc = fmaf(xr[k], W[k * IN_DIM + o], acc);
    msg[(size_t)n * IN_DIM + o] = fmaxf(acc, 0.f);
}

// h = relu(edge_attr @ W_e1 + b_e1)  -> fp16   (depth-invariant)
__global__ void k_edge_h16(const float* __restrict__ ea, const float* __restrict__ W1,
                           const float* __restrict__ b1, __half* __restrict__ h) {
    int e = blockIdx.x;
    int j = threadIdx.x;          // 128
    __shared__ float r[BOND_DIM];
    if (j < BOND_DIM) r[j] = ea[(size_t)e * BOND_DIM + j];
    __syncthreads();
    float acc = b1[j];
    #pragma unroll
    for (int k = 0; k < BOND_DIM; ++k) acc = fmaf(r[k], W1[k * INTERNAL + j], acc);
    h[(size_t)e * INTERNAL + j] = __float2half(fmaxf(acc, 0.f));
}

// fp32 h variant for small-workspace fallback
__global__ void k_edge_h(const float* __restrict__ ea, const float* __restrict__ W1,
                         const float* __restrict__ b1, float* __restrict__ h) {
    int e = blockIdx.x;
    int j = threadIdx.x;          // 128
    __shared__ float r[BOND_DIM];
    if (j < BOND_DIM) r[j] = ea[(size_t)e * BOND_DIM + j];
    __syncthreads();
    float acc = b1[j];
    #pragma unroll
    for (int k = 0; k < BOND_DIM; ++k) acc = fmaf(r[k], W1[k * INTERNAL + j], acc);
    h[(size_t)e * INTERNAL + j] = fmaxf(acc, 0.f);
}

// transpose-convert W2 [128][4096] fp32 -> W2T [4096][128] fp16
__global__ void k_w2t(const float* __restrict__ W2, __half* __restrict__ W2T) {
    int idx = blockIdx.x * 256 + threadIdx.x;     // 524288 total
    int k = idx >> 12;
    int n = idx & 4095;
    W2T[(size_t)n * INTERNAL + k] = __float2half(W2[idx]);
}

// transpose-convert W_fp [64][4096] fp32 -> WfpT [4096][64] fp16
__global__ void k_wfpt(const float* __restrict__ Wfp, __half* __restrict__ WfpT) {
    int idx = blockIdx.x * 256 + threadIdx.x;     // 262144 total
    int k = idx >> 12;
    int n = idx & 4095;
    WfpT[(size_t)n * IN_DIM + k] = __float2half(Wfp[idx]);
}

// per-dst edge counts for the two masks (depth-invariant)
__global__ void k_counts(const float* __restrict__ ea, const int* __restrict__ dst,
                         float* __restrict__ cntC, float* __restrict__ cntS) {
    int e = blockIdx.x * blockDim.x + threadIdx.x;
    if (e >= N_EDGES) return;
    if (ea[(size_t)e * BOND_DIM + (BOND_DIM - 1)] == 0.f) atomicAdd(&cntC[dst[e]], 1.f);
    else atomicAdd(&cntS[dst[e]], 1.f);
}

// One-time MFMA GEMM: w[E,4096] = h16[E,128] @ W2 + b2, stored fp16 row-major.
// SWAPPED operands: D = W2T_frag x h_frag -> D rows = n, cols = e. Each lane
// then holds 4 CONSECUTIVE n for one edge -> packed 8B stores.
__global__ __launch_bounds__(256) void k_wgemm(
    const __half* __restrict__ h16, const __half* __restrict__ W2T,
    const float* __restrict__ b2, __half* __restrict__ w)
{
    const int tid  = threadIdx.x;
    const int lane = tid & 63;
    const int wid  = tid >> 6;
    const int nbase = blockIdx.y * 256 + (wid & 1) * 128;   // 8 n-frags of 16
    const int ebase = blockIdx.x * 64 + (wid >> 1) * 32;    // 2 e-frags of 16
    const int l15 = lane & 15;
    const int kq  = (lane >> 4) * 8;

    const _Float16* hp = (const _Float16*)h16;
    const _Float16* wp = (const _Float16*)W2T;

    // preload h (B operand, col = edge) frags: [ef][kk]
    half8v bh[2][4];
    #pragma unroll
    for (int ef = 0; ef < 2; ++ef) {
        int e = ebase + ef * 16 + l15;
        if (e >= N_EDGES) e = N_EDGES - 1;
        const _Float16* hrow = hp + (size_t)e * INTERNAL;
        #pragma unroll
        for (int kk = 0; kk < 4; ++kk)
            bh[ef][kk] = *(const half8v*)(hrow + kk * 32 + kq);
    }

    float4v acc[8][2];
    #pragma unroll
    for (int ni = 0; ni < 8; ++ni)
        #pragma unroll
        for (int ef = 0; ef < 2; ++ef)
            acc[ni][ef] = (float4v){0.f, 0.f, 0.f, 0.f};

    #pragma unroll
    for (int kk = 0; kk < 4; ++kk) {
        half8v aw[8];                       // A operand (row = n): 8 independent loads
        #pragma unroll
        for (int ni = 0; ni < 8; ++ni) {
            int n = nbase + ni * 16 + l15;
            aw[ni] = *(const half8v*)(wp + (size_t)n * INTERNAL + kk * 32 + kq);
        }
        #pragma unroll
        for (int ni = 0; ni < 8; ++ni) {
            acc[ni][0] = __builtin_amdgcn_mfma_f32_16x16x32_f16(aw[ni], bh[0][kk], acc[ni][0], 0, 0, 0);
            acc[ni][1] = __builtin_amdgcn_mfma_f32_16x16x32_f16(aw[ni], bh[1][kk], acc[ni][1], 0, 0, 0);
        }
    }

    // epilogue: lane holds n0..n0+3 (rows) for edge (col); 8B packed stores
    const int rq = (lane >> 4) * 4;
    #pragma unroll
    for (int ni = 0; ni < 8; ++ni) {
        int n0 = nbase + ni * 16 + rq;
        float4 bv = *(const float4*)&b2[n0];
        #pragma unroll
        for (int ef = 0; ef < 2; ++ef) {
            int e = ebase + ef * 16 + l15;
            if (e < N_EDGES) {
                half4v o;
                o[0] = (_Float16)(acc[ni][ef][0] + bv.x);
                o[1] = (_Float16)(acc[ni][ef][1] + bv.y);
                o[2] = (_Float16)(acc[ni][ef][2] + bv.z);
                o[3] = (_Float16)(acc[ni][ef][3] + bv.w);
                *(half4v*)((_Float16*)w + (size_t)e * 4096 + n0) = o;
            }
        }
    }
}

// Per depth: per_edge[e] = m[src[e]] @ w[e] (64x64 fp16), fused masked scatter-add.
__global__ __launch_bounds__(256) void k_edge_apply(
    const float* __restrict__ msg, const __half* __restrict__ w,
    const int* __restrict__ src, const int* __restrict__ dst,
    const float* __restrict__ ea,
    float* __restrict__ aggC, float* __restrict__ aggS)
{
    const int lane = threadIdx.x & 63;
    const int e = blockIdx.x * 4 + (threadIdx.x >> 6);
    if (e >= N_EDGES) return;
    const float mv = msg[(size_t)src[e] * IN_DIM + lane];
    const half8v* wrow = (const half8v*)((const _Float16*)w + (size_t)e * 4096);
    const int ig = lane >> 3;
    const int oc = lane & 7;
    float acc[8] = {0.f, 0.f, 0.f, 0.f, 0.f, 0.f, 0.f, 0.f};
    #pragma unroll
    for (int t = 0; t < 8; ++t) {
        int i = ig + 8 * t;
        half8v w8 = wrow[i * 8 + oc];
        float mi = __shfl(mv, i);
        #pragma unroll
        for (int j = 0; j < 8; ++j) acc[j] = fmaf(mi, (float)w8[j], acc[j]);
    }
    #pragma unroll
    for (int d = 8; d < 64; d <<= 1)
        #pragma unroll
        for (int j = 0; j < 8; ++j) acc[j] += __shfl_xor(acc[j], d);
    if (ig == 0) {
        float* agg = (ea[(size_t)e * BOND_DIM + (BOND_DIM - 1)] == 0.f) ? aggC : aggS;
        float* p = &agg[(size_t)dst[e] * IN_DIM + oc * 8];
        #pragma unroll
        for (int j = 0; j < 8; ++j) atomicAdd(p + j, acc[j]);
    }
}

// ===== fallback (small workspace): round-1 fused per-edge GEMM =====
__global__ __launch_bounds__(256) void k_per_edge_scatter(
    const float* __restrict__ h, const float* __restrict__ msg,
    const int* __restrict__ src, const int* __restrict__ dst,
    const float* __restrict__ ea,
    const float* __restrict__ W2, const float* __restrict__ b2,
    float* __restrict__ aggC, float* __restrict__ aggS)
{
    __shared__ float m_lds[64][68];
    __shared__ float h_lds[64 * INTERNAL];
    __shared__ float w_lds[4096];
    const int tid = threadIdx.x;
    const int e0 = blockIdx.x * 64;
    const int tx = tid & 15;
    const int ty = tid >> 4;

    for (int v = tid; v < 2048; v += 256) {
        int idx = v * 4;
        int row = idx >> 7, col = idx & 127;
        int e = e0 + row; if (e >= N_EDGES) e = N_EDGES - 1;
        *(float4*)&h_lds[idx] = *(const float4*)&h[(size_t)e * INTERNAL + col];
    }
    for (int v = tid; v < 1024; v += 256) {
        int idx = v * 4;
        int row = idx >> 6, col = idx & 63;
        int e = e0 + row; if (e >= N_EDGES) e = N_EDGES - 1;
        *(float4*)&m_lds[row][col] = *(const float4*)&msg[(size_t)src[e] * IN_DIM + col];
    }

    float acc[4][4];
    #pragma unroll
    for (int j = 0; j < 4; ++j)
        #pragma unroll
        for (int l = 0; l < 4; ++l) acc[j][l] = 0.f;

    for (int k = 0; k <= INTERNAL; ++k) {
        __syncthreads();
        if (k < INTERNAL) {
            const float* wr = W2 + (size_t)k * 4096;
            for (int v = tid; v < 1024; v += 256)
                *(float4*)&w_lds[v * 4] = *(const float4*)&wr[v * 4];
        } else {
            for (int v = tid; v < 1024; v += 256)
                *(float4*)&w_lds[v * 4] = *(const float4*)&b2[v * 4];
        }
        __syncthreads();
        float he[4];
        #pragma unroll
        for (int j = 0; j < 4; ++j)
            he[j] = (k < INTERNAL) ? h_lds[(ty + 16 * j) * INTERNAL + k] : 1.f;
        #pragma unroll 2
        for (int i = 0; i < 64; i += 2) {
            float4 wa = *(const float4*)&w_lds[i * 64 + tx * 4];
            float4 wb = *(const float4*)&w_lds[(i + 1) * 64 + tx * 4];
            #pragma unroll
            for (int j = 0; j < 4; ++j) {
                float2 mvv = *(const float2*)&m_lds[ty + 16 * j][i];
                float pa = he[j] * mvv.x;
                float pb = he[j] * mvv.y;
                acc[j][0] = fmaf(pa, wa.x, fmaf(pb, wb.x, acc[j][0]));
                acc[j][1] = fmaf(pa, wa.y, fmaf(pb, wb.y, acc[j][1]));
                acc[j][2] = fmaf(pa, wa.z, fmaf(pb, wb.z, acc[j][2]));
                acc[j][3] = fmaf(pa, wa.w, fmaf(pb, wb.w, acc[j][3]));
            }
        }
    }

    #pragma unroll
    for (int j = 0; j < 4; ++j) {
        int e = e0 + ty + 16 * j;
        if (e < N_EDGES) {
            float* agg = (ea[(size_t)e * BOND_DIM + (BOND_DIM - 1)] == 0.f) ? aggC : aggS;
            float* p = &agg[(size_t)dst[e] * IN_DIM + tx * 4];
            atomicAdd(p + 0, acc[j][0]);
            atomicAdd(p + 1, acc[j][1]);
            atomicAdd(p + 2, acc[j][2]);
            atomicAdd(p + 3, acc[j][3]);
        }
    }
}

// msg_new = relu(mean_cov + mean_spa + 2*(msg_old @ W_root + b_conv)); fp32 + fp16 copy
__global__ void k_combine(const float* __restrict__ msg_old, const float* __restrict__ Wr,
                          const float* __restrict__ bc,
                          const float* __restrict__ aggC, const float* __restrict__ aggS,
                          const float* __restrict__ cntC, const float* __restrict__ cntS,
                          float* __restrict__ msg_new, __half* __restrict__ msg16) {
    int n = blockIdx.x, o = threadIdx.x;   // 64
    __shared__ float r[IN_DIM];
    r[o] = msg_old[(size_t)n * IN_DIM + o];
    __syncthreads();
    float root = bc[o];
    #pragma unroll
    for (int k = 0; k < IN_DIM; ++k) root = fmaf(r[k], Wr[k * IN_DIM + o], root);
    float cc = cntC[n], cs = cntS[n];
    float mc = (cc > 0.f) ? aggC[(size_t)n * IN_DIM + o] / cc : 0.f;
    float ms = (cs > 0.f) ? aggS[(size_t)n * IN_DIM + o] / cs : 0.f;
    float v = fmaxf(mc + ms + 2.f * root, 0.f);
    msg_new[(size_t)n * IN_DIM + o] = v;
    if (msg16) msg16[(size_t)n * IN_DIM + o] = __float2half(v);
}

// MFMA fused GEMM + relu + add-pool: out[g,:] += sum_n relu(msg16[n] @ WfpT^T + b_fp)
__global__ __launch_bounds__(256) void k_fp_pool_mfma(
    const __half* __restrict__ msg16, const __half* __restrict__ WfpT,
    const float* __restrict__ bfp, const int* __restrict__ gstart,
    float* __restrict__ out)
{
    const int tid = threadIdx.x, lane = tid & 63, wid = tid >> 6;
    const int g = blockIdx.y;
    const int cbase = blockIdx.x * 256 + wid * 64;     // wave: 4 col-frags of 16
    const int l15 = lane & 15;
    const int kq = (lane >> 4) * 8;
    const int rq = (lane >> 4) * 4;

    const _Float16* wt = (const _Float16*)WfpT;
    const _Float16* mp = (const _Float16*)msg16;

    half8v bf[4][2];
    float bias[4];
    #pragma unroll
    for (int nf = 0; nf < 4; ++nf) {
        int n = cbase + nf * 16 + l15;
        #pragma unroll
        for (int kk = 0; kk < 2; ++kk)
            bf[nf][kk] = *(const half8v*)(wt + (size_t)n * IN_DIM + kk * 32 + kq);
        bias[nf] = bfp[n];
    }

    int n0g = gstart[g], n1g = gstart[g + 1];
    int len = n1g - n0g;
    int chunk = (len + (int)gridDim.z - 1) / (int)gridDim.z;
    int rs = n0g + (int)blockIdx.z * chunk;
    int re = min(rs + chunk, n1g);

    float pool[4] = {0.f, 0.f, 0.f, 0.f};
    for (int r = rs; r < re; r += 16) {
        int node = r + l15;
        if (node >= n1g) node = n1g - 1;
        half8v af0 = *(const half8v*)(mp + (size_t)node * IN_DIM + kq);
        half8v af1 = *(const half8v*)(mp + (size_t)node * IN_DIM + 32 + kq);
        #pragma unroll
        for (int nf = 0; nf < 4; ++nf) {
            float4v d = (float4v){0.f, 0.f, 0.f, 0.f};
            d = __builtin_amdgcn_mfma_f32_16x16x32_f16(af0, bf[nf][0], d, 0, 0, 0);
            d = __builtin_amdgcn_mfma_f32_16x16x32_f16(af1, bf[nf][1], d, 0, 0, 0);
            #pragma unroll
            for (int reg = 0; reg < 4; ++reg) {
                int rr = r + rq + reg;
                if (rr < re) pool[nf] += fmaxf(d[reg] + bias[nf], 0.f);
            }
        }
    }
    #pragma unroll
    for (int nf = 0; nf < 4; ++nf) {
        pool[nf] += __shfl_xor(pool[nf], 16);
        pool[nf] += __shfl_xor(pool[nf], 32);
    }
    if (lane < 16) {
        #pragma unroll
        for (int nf = 0; nf < 4; ++nf)
            atomicAdd(&out[(size_t)g * FP_DIM + cbase + nf * 16 + lane], pool[nf]);
    }
}

// fp32 fallback fp_pool
__global__ __launch_bounds__(256) void k_fp_pool(
    const float* __restrict__ msg, const float* __restrict__ Wfp,
    const float* __restrict__ bfp, const int* __restrict__ gstart,
    float* __restrict__ out) {
    int c = blockIdx.x * 256 + threadIdx.x;
    int g = blockIdx.y;
    float w[IN_DIM];
    #pragma unroll
    for (int k = 0; k < IN_DIM; ++k) w[k] = Wfp[(size_t)k * FP_DIM + c];
    float bias = bfp[c];
    int n0 = gstart[g], n1 = gstart[g + 1];
    int len = n1 - n0;
    int chunk = (len + (int)gridDim.z - 1) / (int)gridDim.z;
    int s = n0 + (int)blockIdx.z * chunk;
    int e = min(s + chunk, n1);
    float acc = 0.f;
    __shared__ float mr[8][IN_DIM];
    for (int nb = s; nb < e; nb += 8) {
        __syncthreads();
        int cnt = min(8, e - nb);
        for (int v = (int)threadIdx.x; v < cnt * IN_DIM; v += 256)
            ((float*)mr)[v] = msg[(size_t)nb * IN_DIM + v];
        __syncthreads();
        for (int rr = 0; rr < cnt; ++rr) {
            float sv = bias;
            #pragma unroll
            for (int k = 0; k < IN_DIM; k += 4) {
                float4 mv = *(const float4*)&mr[rr][k];
                sv = fmaf(mv.x, w[k], sv);
                sv = fmaf(mv.y, w[k + 1], sv);
                sv = fmaf(mv.z, w[k + 2], sv);
                sv = fmaf(mv.w, w[k + 3], sv);
            }
            acc += fmaxf(sv, 0.f);
        }
    }
    atomicAdd(&out[(size_t)g * FP_DIM + c], acc);
}

extern "C" void kernel_launch(void* const* d_in, const int* in_sizes, int n_in,
                              void* d_out, int out_size, void* d_ws, size_t ws_size,
                              hipStream_t stream) {
    const float* x        = (const float*)d_in[0];
    const int*   eidx     = (const int*)d_in[1];
    const float* ea       = (const float*)d_in[2];
    const int*   batch    = (const int*)d_in[3];
    const float* W_ae     = (const float*)d_in[4];
    const float* b_ae     = (const float*)d_in[5];
    const float* W_e1     = (const float*)d_in[6];
    const float* b_e1     = (const float*)d_in[7];
    const float* W_e2     = (const float*)d_in[8];
    const float* b_e2     = (const float*)d_in[9];
    const float* W_root   = (const float*)d_in[10];
    const float* b_conv   = (const float*)d_in[11];
    const float* W_fp     = (const float*)d_in[12];
    const float* b_fp     = (const float*)d_in[13];
    const int* src = eidx;
    const int* dst = eidx + N_EDGES;
    float* out = (float*)d_out;

    hipMemsetAsync(out, 0, (size_t)out_size * sizeof(float), stream);

    float* ws   = (float*)d_ws;
    float* msgA = ws;
    float* msgB = msgA + 640000;
    float* aggC = msgB + 640000;
    float* aggS = aggC + 640000;
    float* cntC = aggS + 640000;
    float* cntS = cntC + 10000;
    int*   gst  = (int*)(cntS + 10000);                 // 32 ints

    // big path extras (fp16)
    __half* h16   = (__half*)(gst + 32);
    __half* W2T   = h16 + (size_t)N_EDGES * INTERNAL;
    __half* wbig  = W2T + (size_t)4096 * INTERNAL;
    __half* msg16 = wbig + (size_t)N_EDGES * 4096;
    __half* WfpT  = msg16 + (size_t)N_NODES * IN_DIM;

    size_t base_f32 = 4 * 640000 + 2 * 10000 + 32;
    size_t need_big = base_f32 * 4
                    + ((size_t)N_EDGES * INTERNAL + (size_t)4096 * INTERNAL
                       + (size_t)N_EDGES * 4096 + (size_t)N_NODES * IN_DIM
                       + (size_t)FP_DIM * IN_DIM) * 2;
    size_t need_small = (base_f32 + (size_t)N_EDGES * INTERNAL) * 4;
    if (ws_size < need_small) return;   // fail loudly (out stays 0)

    hipMemsetAsync(cntC, 0, 2 * (size_t)N_NODES * sizeof(float), stream);
    k_bounds<<<1, 32, 0, stream>>>(batch, gst);
    k_atom_expand<<<N_NODES, 64, 0, stream>>>(x, W_ae, b_ae, msgA);
    k_counts<<<(N_EDGES + 255) / 256, 256, 0, stream>>>(ea, dst, cntC, cntS);

    bool big = (ws_size >= need_big);
    float* hf32 = (float*)(gst + 32);

    if (big) {
        k_edge_h16<<<N_EDGES, 128, 0, stream>>>(ea, W_e1, b_e1, h16);
        k_w2t<<<(4096 * INTERNAL) / 256, 256, 0, stream>>>(W_e2, W2T);
        k_wfpt<<<(FP_DIM * IN_DIM) / 256, 256, 0, stream>>>(W_fp, WfpT);
        k_wgemm<<<dim3((N_EDGES + 63) / 64, 4096 / 256), 256, 0, stream>>>(
            h16, W2T, b_e2, wbig);
    } else {
        k_edge_h<<<N_EDGES, 128, 0, stream>>>(ea, W_e1, b_e1, hf32);
    }

    float* cur = msgA;
    float* nxt = msgB;
    for (int d = 0; d < DEPTH; ++d) {
        hipMemsetAsync(aggC, 0, 2 * (size_t)N_NODES * IN_DIM * sizeof(float), stream);
        if (big) {
            k_edge_apply<<<(N_EDGES + 3) / 4, 256, 0, stream>>>(
                cur, wbig, src, dst, ea, aggC, aggS);
            k_combine<<<N_NODES, 64, 0, stream>>>(cur, W_root, b_conv, aggC, aggS,
                                                  cntC, cntS, nxt, msg16);
            k_fp_pool_mfma<<<dim3(FP_DIM / 256, N_GRAPHS, 4), 256, 0, stream>>>(
                msg16, WfpT, b_fp, gst, out);
        } else {
            k_per_edge_scatter<<<(N_EDGES + 63) / 64, 256, 0, stream>>>(
                hf32, cur, src, dst, ea, W_e2, b_e2, aggC, aggS);
            k_combine<<<N_NODES, 64, 0, stream>>>(cur, W_root, b_conv, aggC, aggS,
                                                  cntC, cntS, nxt, (__half*)nullptr);
            k_fp_pool<<<dim3(FP_DIM / 256, N_GRAPHS, 4), 256, 0, stream>>>(
                nxt, W_fp, b_fp, gst, out);
        }
        float* t = cur; cur = nxt; nxt = t;
    }
}

// Round 4
// 598.218 us; speedup vs baseline: 3.2545x; 1.0006x over previous
//
#include <hip/hip_runtime.h>
#include <hip/hip_fp16.h>

#define N_NODES 10000
#define N_EDGES 30000
#define NODE_DIM 75
#define BOND_DIM 16
#define IN_DIM 64
#define INTERNAL 128
#define FP_DIM 4096
#define N_GRAPHS 16
#define DEPTH 3
#define K_TOT 8256          // 128*64 + 64 (bias block, h==1)
#define KSTEPS 258          // K_TOT / 32

typedef _Float16 half8v __attribute__((ext_vector_type(8)));
typedef float float4v __attribute__((ext_vector_type(4)));

// graph boundaries via binary search on sorted batch
__global__ void k_bounds(const int* __restrict__ batch, int* __restrict__ gstart) {
    int g = threadIdx.x;
    if (g > N_GRAPHS) return;
    int lo = 0, hi = N_NODES;
    while (lo < hi) { int mid = (lo + hi) >> 1; if (batch[mid] < g) lo = mid + 1; else hi = mid; }
    gstart[g] = lo;
}

// msg0 = relu(x @ W_ae + b_ae); writes fp32 + fp16
__global__ void k_atom_expand(const float* __restrict__ x, const float* __restrict__ W,
                              const float* __restrict__ b, float* __restrict__ msg,
                              __half* __restrict__ msg16) {
    int n = blockIdx.x;
    int o = threadIdx.x;          // 64
    __shared__ float xr[NODE_DIM];
    if (o < NODE_DIM) xr[o] = x[(size_t)n * NODE_DIM + o];
    if (o + 64 < NODE_DIM) xr[o + 64] = x[(size_t)n * NODE_DIM + o + 64];
    __syncthreads();
    float acc = b[o];
    #pragma unroll
    for (int k = 0; k < NODE_DIM; ++k) acc = fmaf(xr[k], W[k * IN_DIM + o], acc);
    float v = fmaxf(acc, 0.f);
    msg[(size_t)n * IN_DIM + o] = v;
    msg16[(size_t)n * IN_DIM + o] = __float2half(v);
}

// h = relu(edge_attr @ W_e1 + b_e1) -> fp16  (depth-invariant)
__global__ void k_edge_h16(const float* __restrict__ ea, const float* __restrict__ W1,
                           const float* __restrict__ b1, __half* __restrict__ h) {
    int e = blockIdx.x;
    int j = threadIdx.x;          // 128
    __shared__ float r[BOND_DIM];
    if (j < BOND_DIM) r[j] = ea[(size_t)e * BOND_DIM + j];
    __syncthreads();
    float acc = b1[j];
    #pragma unroll
    for (int k = 0; k < BOND_DIM; ++k) acc = fmaf(r[k], W1[k * INTERNAL + j], acc);
    h[(size_t)e * INTERNAL + j] = __float2half(fmaxf(acc, 0.f));
}

// W2BT[o][K] fp16, K=k*64+i: = W2[k][i*64+o] for k<128; = b2[i*64+o] for K>=8192
__global__ void k_w2bt(const float* __restrict__ W2, const float* __restrict__ b2,
                       __half* __restrict__ W2BT) {
    int K = blockIdx.x * 64 + threadIdx.x;   // 0..8319 (grid.x = 130)
    int o = blockIdx.y;                       // 0..63
    int k = K >> 6, i = K & 63;
    float v = (k < 128) ? W2[(size_t)k * 4096 + i * 64 + o] : b2[i * 64 + o];
    W2BT[(size_t)o * K_TOT + K] = __float2half(v);
}

// WfpT [4096][64] fp16 from W_fp [64][4096]
__global__ void k_wfpt(const float* __restrict__ Wfp, __half* __restrict__ WfpT) {
    int idx = blockIdx.x * 256 + threadIdx.x;     // 262144
    int k = idx >> 12;
    int n = idx & 4095;
    WfpT[(size_t)n * IN_DIM + k] = __float2half(Wfp[idx]);
}

// per-dst edge counts (depth-invariant)
__global__ void k_counts(const float* __restrict__ ea, const int* __restrict__ dst,
                         float* __restrict__ cntC, float* __restrict__ cntS) {
    int e = blockIdx.x * blockDim.x + threadIdx.x;
    if (e >= N_EDGES) return;
    if (ea[(size_t)e * BOND_DIM + (BOND_DIM - 1)] == 0.f) atomicAdd(&cntC[dst[e]], 1.f);
    else atomicAdd(&cntS[dst[e]], 1.f);
}

// Per depth: per_edge[e][o] = sum_K A[e][K]*W2BT[o][K], A[e][k*64+i]=h[e][k]*m[src[e]][i]
// (bias folded as K-block 8192.. with h==1). 64 edges/block, 8 waves = 8 K-parts,
// LDS-atomic reduce, fused masked scatter-add to aggC/aggS.
__global__ __launch_bounds__(512) void k_edge_mfma(
    const __half* __restrict__ h16, const __half* __restrict__ msg16,
    const __half* __restrict__ W2BT,
    const int* __restrict__ src, const int* __restrict__ dst,
    const float* __restrict__ ea,
    float* __restrict__ aggC, float* __restrict__ aggS)
{
    __shared__ _Float16 h_lds[64][136];   // padded: 272B row stride (16B aligned)
    __shared__ float red[64][66];
    const int tid  = threadIdx.x;
    const int lane = tid & 63;
    const int wid  = tid >> 6;            // 0..7 = K-part
    const int e0   = blockIdx.x * 64;
    const int l15  = lane & 15;
    const int lg   = lane >> 4;           // 0..3

    // zero reduction tile
    for (int v = tid; v < 64 * 66; v += 512) ((float*)red)[v] = 0.f;

    // stage h tile [64][128] -> padded LDS
    {
        int row = tid >> 3;
        int col = (tid & 7) * 16;
        int e = e0 + row; if (e >= N_EDGES) e = N_EDGES - 1;
        const _Float16* hr = (const _Float16*)h16 + (size_t)e * INTERNAL + col;
        *(half8v*)&h_lds[row][col]     = *(const half8v*)hr;
        *(half8v*)&h_lds[row][col + 8] = *(const half8v*)(hr + 8);
    }

    // m fragments (register gather): [etile], i0 variants a (i<32) / b (i>=32)
    half8v mfa[4], mfb[4];
    #pragma unroll
    for (int et = 0; et < 4; ++et) {
        int e = e0 + et * 16 + l15; if (e >= N_EDGES) e = N_EDGES - 1;
        int s = src[e];
        const _Float16* mr = (const _Float16*)msg16 + (size_t)s * IN_DIM + lg * 8;
        mfa[et] = *(const half8v*)mr;
        mfb[et] = *(const half8v*)(mr + 32);
    }
    __syncthreads();

    float4v acc[4][4];                    // [etile][oblk]
    #pragma unroll
    for (int et = 0; et < 4; ++et)
        #pragma unroll
        for (int ob = 0; ob < 4; ++ob)
            acc[et][ob] = (float4v){0.f, 0.f, 0.f, 0.f};

    // per-oblk B base pointers (advance 32 halfs per kstep)
    const _Float16* wb[4];
    #pragma unroll
    for (int ob = 0; ob < 4; ++ob)
        wb[ob] = (const _Float16*)W2BT + (size_t)(ob * 16 + l15) * K_TOT + lg * 8;

    const int ks0 = (wid * KSTEPS) >> 3;
    const int ks1 = ((wid + 1) * KSTEPS) >> 3;

    #pragma unroll 2
    for (int ks = ks0; ks < ks1; ++ks) {
        const int k = ks >> 1;            // wave-uniform
        const bool hi = ks & 1;
        half8v A[4];
        #pragma unroll
        for (int et = 0; et < 4; ++et) {
            _Float16 hv = (_Float16)1.0f;
            if (k < 128) hv = h_lds[et * 16 + l15][k];
            half8v mm = hi ? mfb[et] : mfa[et];
            A[et] = mm * hv;
        }
        #pragma unroll
        for (int ob = 0; ob < 4; ++ob) {
            half8v B = *(const half8v*)(wb[ob] + (size_t)ks * 32);
            #pragma unroll
            for (int et = 0; et < 4; ++et)
                acc[et][ob] = __builtin_amdgcn_mfma_f32_16x16x32_f16(A[et], B, acc[et][ob], 0, 0, 0);
        }
    }

    // reduce K-part partials in LDS (atomic f32)
    #pragma unroll
    for (int et = 0; et < 4; ++et)
        #pragma unroll
        for (int ob = 0; ob < 4; ++ob)
            #pragma unroll
            for (int r = 0; r < 4; ++r)
                atomicAdd(&red[et * 16 + lg * 4 + r][ob * 16 + l15], acc[et][ob][r]);
    __syncthreads();

    // masked scatter: wave wid handles 8 edges, lane = output o
    for (int r = 0; r < 8; ++r) {
        int er = wid * 8 + r;
        int e = e0 + er;
        if (e < N_EDGES) {
            float v = red[er][lane];
            float* agg = (ea[(size_t)e * BOND_DIM + (BOND_DIM - 1)] == 0.f) ? aggC : aggS;
            atomicAdd(&agg[(size_t)dst[e] * IN_DIM + lane], v);
        }
    }
}

// msg_new = relu(mean_cov + mean_spa + 2*(msg_old @ W_root + b_conv)); fp32 + fp16
__global__ void k_combine(const float* __restrict__ msg_old, const float* __restrict__ Wr,
                          const float* __restrict__ bc,
                          const float* __restrict__ aggC, const float* __restrict__ aggS,
                          const float* __restrict__ cntC, const float* __restrict__ cntS,
                          float* __restrict__ msg_new, __half* __restrict__ msg16) {
    int n = blockIdx.x, o = threadIdx.x;   // 64
    __shared__ float r[IN_DIM];
    r[o] = msg_old[(size_t)n * IN_DIM + o];
    __syncthreads();
    float root = bc[o];
    #pragma unroll
    for (int k = 0; k < IN_DIM; ++k) root = fmaf(r[k], Wr[k * IN_DIM + o], root);
    float cc = cntC[n], cs = cntS[n];
    float mc = (cc > 0.f) ? aggC[(size_t)n * IN_DIM + o] / cc : 0.f;
    float ms = (cs > 0.f) ? aggS[(size_t)n * IN_DIM + o] / cs : 0.f;
    float v = fmaxf(mc + ms + 2.f * root, 0.f);
    msg_new[(size_t)n * IN_DIM + o] = v;
    msg16[(size_t)n * IN_DIM + o] = __float2half(v);
}

// MFMA fused GEMM + relu + add-pool: out[g,:] += sum_n relu(msg16[n] @ WfpT^T + b_fp)
__global__ __launch_bounds__(256) void k_fp_pool_mfma(
    const __half* __restrict__ msg16, const __half* __restrict__ WfpT,
    const float* __restrict__ bfp, const int* __restrict__ gstart,
    float* __restrict__ out)
{
    const int tid = threadIdx.x, lane = tid & 63, wid = tid >> 6;
    const int g = blockIdx.y;
    const int cbase = blockIdx.x * 256 + wid * 64;
    const int l15 = lane & 15;
    const int kq = (lane >> 4) * 8;
    const int rq = (lane >> 4) * 4;

    const _Float16* wt = (const _Float16*)WfpT;
    const _Float16* mp = (const _Float16*)msg16;

    half8v bf[4][2];
    float bias[4];
    #pragma unroll
    for (int nf = 0; nf < 4; ++nf) {
        int n = cbase + nf * 16 + l15;
        #pragma unroll
        for (int kk = 0; kk < 2; ++kk)
            bf[nf][kk] = *(const half8v*)(wt + (size_t)n * IN_DIM + kk * 32 + kq);
        bias[nf] = bfp[n];
    }

    int n0g = gstart[g], n1g = gstart[g + 1];
    int len = n1g - n0g;
    int chunk = (len + (int)gridDim.z - 1) / (int)gridDim.z;
    int rs = n0g + (int)blockIdx.z * chunk;
    int re = min(rs + chunk, n1g);

    float pool[4] = {0.f, 0.f, 0.f, 0.f};
    for (int r = rs; r < re; r += 16) {
        int node = r + l15;
        if (node >= n1g) node = n1g - 1;
        half8v af0 = *(const half8v*)(mp + (size_t)node * IN_DIM + kq);
        half8v af1 = *(const half8v*)(mp + (size_t)node * IN_DIM + 32 + kq);
        #pragma unroll
        for (int nf = 0; nf < 4; ++nf) {
            float4v d = (float4v){0.f, 0.f, 0.f, 0.f};
            d = __builtin_amdgcn_mfma_f32_16x16x32_f16(af0, bf[nf][0], d, 0, 0, 0);
            d = __builtin_amdgcn_mfma_f32_16x16x32_f16(af1, bf[nf][1], d, 0, 0, 0);
            #pragma unroll
            for (int reg = 0; reg < 4; ++reg) {
                int rr = r + rq + reg;
                if (rr < re) pool[nf] += fmaxf(d[reg] + bias[nf], 0.f);
            }
        }
    }
    #pragma unroll
    for (int nf = 0; nf < 4; ++nf) {
        pool[nf] += __shfl_xor(pool[nf], 16);
        pool[nf] += __shfl_xor(pool[nf], 32);
    }
    if (lane < 16) {
        #pragma unroll
        for (int nf = 0; nf < 4; ++nf)
            atomicAdd(&out[(size_t)g * FP_DIM + cbase + nf * 16 + lane], pool[nf]);
    }
}

extern "C" void kernel_launch(void* const* d_in, const int* in_sizes, int n_in,
                              void* d_out, int out_size, void* d_ws, size_t ws_size,
                              hipStream_t stream) {
    const float* x        = (const float*)d_in[0];
    const int*   eidx     = (const int*)d_in[1];
    const float* ea       = (const float*)d_in[2];
    const int*   batch    = (const int*)d_in[3];
    const float* W_ae     = (const float*)d_in[4];
    const float* b_ae     = (const float*)d_in[5];
    const float* W_e1     = (const float*)d_in[6];
    const float* b_e1     = (const float*)d_in[7];
    const float* W_e2     = (const float*)d_in[8];
    const float* b_e2     = (const float*)d_in[9];
    const float* W_root   = (const float*)d_in[10];
    const float* b_conv   = (const float*)d_in[11];
    const float* W_fp     = (const float*)d_in[12];
    const float* b_fp     = (const float*)d_in[13];
    const int* src = eidx;
    const int* dst = eidx + N_EDGES;
    float* out = (float*)d_out;

    hipMemsetAsync(out, 0, (size_t)out_size * sizeof(float), stream);

    float* ws   = (float*)d_ws;
    float* msgA = ws;
    float* msgB = msgA + 640000;
    float* aggC = msgB + 640000;
    float* aggS = aggC + 640000;
    float* cntC = aggS + 640000;
    float* cntS = cntC + 10000;
    int*   gst  = (int*)(cntS + 10000);                 // 32 ints

    __half* h16   = (__half*)(gst + 32);
    __half* W2BT  = h16 + (size_t)N_EDGES * INTERNAL;   // 3,840,000 halfs
    __half* msg16 = W2BT + (size_t)IN_DIM * K_TOT;      // 528,384 halfs
    __half* WfpT  = msg16 + (size_t)N_NODES * IN_DIM;   // 640,000 halfs

    size_t need = (4ull * 640000 + 2 * 10000 + 32) * 4
                + ((size_t)N_EDGES * INTERNAL + (size_t)IN_DIM * K_TOT
                   + (size_t)N_NODES * IN_DIM + (size_t)FP_DIM * IN_DIM) * 2;
    if (ws_size < need) return;   // fail loudly (out stays 0)

    hipMemsetAsync(cntC, 0, 2 * (size_t)N_NODES * sizeof(float), stream);
    k_bounds<<<1, 32, 0, stream>>>(batch, gst);
    k_atom_expand<<<N_NODES, 64, 0, stream>>>(x, W_ae, b_ae, msgA, msg16);
    k_counts<<<(N_EDGES + 255) / 256, 256, 0, stream>>>(ea, dst, cntC, cntS);
    k_edge_h16<<<N_EDGES, 128, 0, stream>>>(ea, W_e1, b_e1, h16);
    k_w2bt<<<dim3(K_TOT / 64, IN_DIM), 64, 0, stream>>>(W_e2, b_e2, W2BT);
    k_wfpt<<<(FP_DIM * IN_DIM) / 256, 256, 0, stream>>>(W_fp, WfpT);

    float* cur = msgA;
    float* nxt = msgB;
    for (int d = 0; d < DEPTH; ++d) {
        hipMemsetAsync(aggC, 0, 2 * (size_t)N_NODES * IN_DIM * sizeof(float), stream);
        k_edge_mfma<<<(N_EDGES + 63) / 64, 512, 0, stream>>>(
            h16, msg16, W2BT, src, dst, ea, aggC, aggS);
        k_combine<<<N_NODES, 64, 0, stream>>>(cur, W_root, b_conv, aggC, aggS,
                                              cntC, cntS, nxt, msg16);
        k_fp_pool_mfma<<<dim3(FP_DIM / 256, N_GRAPHS, 4), 256, 0, stream>>>(
            msg16, WfpT, b_fp, gst, out);
        float* t = cur; cur = nxt; nxt = t;
    }
}